// Round 1
// 56.496 us; speedup vs baseline: 1.0096x; 1.0096x over previous
//
#include <hip/hip_runtime.h>

// 54x54-bit array multiplier over {0,1}-valued float bit-vectors.
// The reference's differentiable gate network (XOR=a+b-2ab, AND=ab, OR=a+b-ab,
// ripple-carry adds) is EXACT integer multiplication when inputs are exactly
// 0.0/1.0. So: pack bits -> 64x64->128 multiply -> unpack.
//
// One 64-lane wave per batch row:
//   - lane i (i<54) reads A[row][i], B[row][i]  (coalesced dword loads)
//   - __ballot packs each into a wave-uniform uint64 (scalar regs)
//   - lo = a*b, hi = __umul64hi(a,b)  => 108-bit product (scalar ALU)
//   - epilogue: lanes 0..26 each write one float4 (4 product bits, 16B/lane)
//     -> single global_store_dwordx4 per row instead of two dword stores.
//     Alignment: row*108 floats = row*432 B, 432 = 27*16, j*4 B % 16 == 0.
#define BITS 54
#define OUT_BITS 108

__global__ __launch_bounds__(256) void mult54_kernel(const float* __restrict__ A,
                                                     const float* __restrict__ B,
                                                     float* __restrict__ out,
                                                     int batch) {
    const int gtid = blockIdx.x * blockDim.x + threadIdx.x;
    const int row  = gtid >> 6;          // one wave (64 lanes) per row
    const int lane = threadIdx.x & 63;
    if (row >= batch) return;            // whole waves exit together

    const float* __restrict__ arow = A + (size_t)row * BITS;
    const float* __restrict__ brow = B + (size_t)row * BITS;

    bool abit = false, bbit = false;
    if (lane < BITS) {
        abit = arow[lane] > 0.5f;
        bbit = brow[lane] > 0.5f;
    }
    unsigned long long a = __ballot(abit);   // bit i of mask = lane i's bit -> LSB-first int
    unsigned long long b = __ballot(bbit);

    unsigned long long lo = a * b;
    unsigned long long hi = __umul64hi(a, b);   // bits 64..107 live in hi[0..43]

    // 108 output bits -> 27 lanes x float4 (one dwordx4 store per row).
    if (lane < OUT_BITS / 4) {
        const int j = lane * 4;          // starting output bit for this lane
        unsigned nib = (j < 64) ? (unsigned)((lo >> j) & 0xFull)
                                : (unsigned)((hi >> (j - 64)) & 0xFull);
        float4 v;
        v.x = (float)(nib & 1u);
        v.y = (float)((nib >> 1) & 1u);
        v.z = (float)((nib >> 2) & 1u);
        v.w = (float)((nib >> 3) & 1u);
        *reinterpret_cast<float4*>(out + (size_t)row * OUT_BITS + j) = v;
    }
}

extern "C" void kernel_launch(void* const* d_in, const int* in_sizes, int n_in,
                              void* d_out, int out_size, void* d_ws, size_t ws_size,
                              hipStream_t stream) {
    const float* A = (const float*)d_in[0];
    const float* B = (const float*)d_in[1];
    float* out = (float*)d_out;

    const int batch = in_sizes[0] / BITS;      // 8192
    const int threads_total = batch * 64;      // one wave per row
    const int block = 256;
    const int grid = (threads_total + block - 1) / block;

    hipLaunchKernelGGL(mult54_kernel, dim3(grid), dim3(block), 0, stream,
                       A, B, out, batch);
}